// Round 9
// baseline (256.548 us; speedup 1.0000x reference)
//
#include <hip/hip_runtime.h>
#include <hip/hip_bf16.h>
#include <stdint.h>

// Problem constants (fixed by the reference)
#define NTOK 32768
#define HDIM 512
#define ODIM 512
#define NEXP 16

// GEMM tile config: TM=64 x TN=128 per block, 4 waves in 2x2; NO LDS staging (R9).
#define TM 64
#define TN 128
#define MTILES 64   // 64 tiles x 64 rows = 4096 tokens/expert capacity (>40 sigma margin)

// counts[e] lives at counts[e*CSTRIDE]: one counter per 128B line -> 16-way parallel L2 atomics
#define CSTRIDE 32

#define GATE_BLKS (NTOK / 16)                      // 2048 gate blocks, 16 tokens each
#define CVT_BLKS (NEXP * ODIM * HDIM / 8 / 256)    // 2048 We-cvt blocks

typedef __bf16 bf16x8 __attribute__((ext_vector_type(8)));
typedef float  floatx4 __attribute__((ext_vector_type(4)));

__device__ __forceinline__ unsigned pk2(unsigned lo, unsigned hi) {
  return (lo >> 16) | (hi & 0xffff0000u);
}

__device__ __forceinline__ bf16x8 asbf8(uint4 u) { bf16x8 v; __builtin_memcpy(&v, &u, 16); return v; }

// exact 3-way bf16 truncation split of 8 floats: f = H + M + L exactly
__device__ __forceinline__ void split3(float4 a, float4 b, uint4* H, uint4* M, uint4* L) {
  float f[8] = {a.x, a.y, a.z, a.w, b.x, b.y, b.z, b.w};
  unsigned h[8], m[8], l[8];
#pragma unroll
  for (int j = 0; j < 8; ++j) {
    union { float F; unsigned U; } u; u.F = f[j];
    h[j] = u.U & 0xffff0000u;
    union { unsigned U; float F; } hv; hv.U = h[j];
    float r1 = f[j] - hv.F;                 // exact
    union { float F; unsigned U; } r1u; r1u.F = r1;
    m[j] = r1u.U & 0xffff0000u;
    union { unsigned U; float F; } mv; mv.U = m[j];
    float r2 = r1 - mv.F;                   // exact, fits bf16
    union { float F; unsigned U; } r2u; r2u.F = r2;
    l[j] = r2u.U;
  }
  H->x = pk2(h[0], h[1]); H->y = pk2(h[2], h[3]); H->z = pk2(h[4], h[5]); H->w = pk2(h[6], h[7]);
  M->x = pk2(m[0], m[1]); M->y = pk2(m[2], m[3]); M->z = pk2(m[4], m[5]); M->w = pk2(m[6], m[7]);
  L->x = pk2(l[0], l[1]); L->y = pk2(l[2], l[3]); L->z = pk2(l[4], l[5]); L->w = pk2(l[6], l[7]);
}

// ---------------- fused prep: gate (16 tok/block) + We fp32->bf16 cvt (R7-exact) ------
__global__ __launch_bounds__(256, 4) void fused_prep(const float* __restrict__ x,
                                                     const float* __restrict__ Wg,
                                                     const float* __restrict__ bg,
                                                     const float* __restrict__ We,
                                                     int* __restrict__ counts,
                                                     int* __restrict__ buckets,
                                                     unsigned short* __restrict__ xbf,
                                                     unsigned short* __restrict__ webf) {
  __shared__ __align__(16) float red[4][16][20];   // [wave][token][expert], stride 20

  int bid = blockIdx.x;
  int t = threadIdx.x;

  if (bid >= GATE_BLKS) {
    // ---- We cvt block: 8 floats/thread, contiguous ----
    int i = (bid - GATE_BLKS) * 256 + t;
    const float4* src = (const float4*)We;
    float4 a = src[2 * i];
    float4 b = src[2 * i + 1];
    union { float F; unsigned U; } u[8] = {{a.x},{a.y},{a.z},{a.w},{b.x},{b.y},{b.z},{b.w}};
    uint4 o;
    o.x = pk2(u[0].U, u[1].U); o.y = pk2(u[2].U, u[3].U);
    o.z = pk2(u[4].U, u[5].U); o.w = pk2(u[6].U, u[7].U);
    ((uint4*)webf)[i] = o;
    return;
  }

  // ---- gate block: 16 tokens ----
  int lane = t & 63;
  int w = t >> 6;               // wave w covers k-range [w*128, w*128+128)
  int tok0 = bid * 16;
  int fr = lane & 15;           // A: token row; B: expert column
  int quad = lane >> 4;         // 8-float chunk within the 32-float k-step

  const float* xb0 = x + (size_t)(tok0 + fr) * HDIM + w * 128 + quad * 8;
  const float* wg0 = Wg + (size_t)fr * HDIM + w * 128 + quad * 8;

  floatx4 acc = {};

  // prefetch si=0 x
  float4 xa = *(const float4*)(xb0);
  float4 xv = *(const float4*)(xb0 + 4);

#pragma unroll
  for (int si = 0; si < 4; ++si) {
    int s = w * 4 + si;
    // B-frags from global (L2-hot 32KB), split in registers — bit-identical to staged path
    float4 wa = *(const float4*)(wg0 + si * 32);
    float4 wb = *(const float4*)(wg0 + si * 32 + 4);
    uint4 BH, BM, BL;
    split3(wa, wb, &BH, &BM, &BL);
    bf16x8 bh = asbf8(BH), bm = asbf8(BM), bl = asbf8(BL);

    float4 nxa, nxv;
    if (si < 3) {
      nxa = *(const float4*)(xb0 + (si + 1) * 32);
      nxv = *(const float4*)(xb0 + (si + 1) * 32 + 4);
    }

    uint4 H, M, L;
    split3(xa, xv, &H, &M, &L);
    *(uint4*)(xbf + (size_t)(tok0 + fr) * HDIM + s * 32 + quad * 8) = H;  // fused x->bf16
    bf16x8 ah = asbf8(H), am = asbf8(M), al = asbf8(L);
    acc = __builtin_amdgcn_mfma_f32_16x16x32_bf16(ah, bh, acc, 0, 0, 0);
    acc = __builtin_amdgcn_mfma_f32_16x16x32_bf16(ah, bm, acc, 0, 0, 0);
    acc = __builtin_amdgcn_mfma_f32_16x16x32_bf16(am, bh, acc, 0, 0, 0);
    acc = __builtin_amdgcn_mfma_f32_16x16x32_bf16(am, bm, acc, 0, 0, 0);
    acc = __builtin_amdgcn_mfma_f32_16x16x32_bf16(ah, bl, acc, 0, 0, 0);
    acc = __builtin_amdgcn_mfma_f32_16x16x32_bf16(al, bh, acc, 0, 0, 0);
    acc = __builtin_amdgcn_mfma_f32_16x16x32_bf16(am, bl, acc, 0, 0, 0);
    acc = __builtin_amdgcn_mfma_f32_16x16x32_bf16(al, bm, acc, 0, 0, 0);

    if (si < 3) { xa = nxa; xv = nxv; }
  }

  // cross-wave reduction: C/D layout col(lane&15)=expert, row=quad*4+i=token
#pragma unroll
  for (int i = 0; i < 4; ++i)
    red[w][quad * 4 + i][fr] = acc[i];
  __syncthreads();

  if (t < 16) {
    int r = t;    // token row
    float4 tot4[4];
#pragma unroll
    for (int eq = 0; eq < 4; ++eq) tot4[eq] = *(const float4*)&bg[eq * 4];
#pragma unroll
    for (int ww = 0; ww < 4; ++ww)
#pragma unroll
      for (int eq = 0; eq < 4; ++eq) {
        float4 v = *(const float4*)&red[ww][r][eq * 4];
        tot4[eq].x += v.x; tot4[eq].y += v.y; tot4[eq].z += v.z; tot4[eq].w += v.w;
      }
    float tot[16];
#pragma unroll
    for (int eq = 0; eq < 4; ++eq) {
      tot[eq * 4 + 0] = tot4[eq].x; tot[eq * 4 + 1] = tot4[eq].y;
      tot[eq * 4 + 2] = tot4[eq].z; tot[eq * 4 + 3] = tot4[eq].w;
    }
    float bv = tot[0]; int bi = 0;
#pragma unroll
    for (int e = 1; e < NEXP; ++e) if (tot[e] > bv) { bv = tot[e]; bi = e; }  // numpy first-index tie-break

    int token = tok0 + r;
    // staggered expert order: blocks hit different counters at any instant
    for (int ee = 0; ee < NEXP; ++ee) {
      int e = (ee + bid) & 15;
      unsigned long long mask = __ballot(bi == e);   // only lanes t<16 active
      if (mask) {
        int leader = __builtin_ctzll(mask);
        int base = 0;
        if (lane == leader) base = atomicAdd(&counts[e << 5], (int)__popcll(mask));
        base = __shfl(base, leader, 64);
        if (bi == e) {
          int rank = (int)__popcll(mask & ((1ull << lane) - 1ull));
          buckets[e * NTOK + base + rank] = token;
        }
      }
    }
  }
}

// ---------------- gathered-A GEMM, barrier-free direct-from-L2 fragments (R9) ---------
// With the XCD swizzle (R8, FETCH 53->29 MB verified) both operand panels are L2-hot.
// LDS staging + per-iter vmcnt(0)+barrier (the 16 drains that coupled all 4 waves to
// the slowest load; MfmaUtil 13% with every pipe at ~25%) is deleted. Each wave loads
// its MFMA fragments DIRECTLY from global into registers:
//   A frag (mt): xbf[toks[wm+mt*16+fr]*512 + s*32 + quad*8]  (16B/lane)
//   B frag (nt): webf[(e*512+o0+wn+nt*16+fr)*512 + s*32 + quad*8]
// identical content to what the LDS path delivered (the old aoff/boff swizzle was
// LDS-bank bookkeeping only) -> bit-identical numerics. k-loop fully unrolled (16
// steps) with register double-buffering: load step s+1's 6 frags while MFMAing step
// s. Zero barriers after the toks load; 16 independent wave streams per CU hide L2
// latency via ILP+TLP. L2 read traffic doubles (no wave sharing) but stays under the
// ~23us L2-BW floor.
__global__ __launch_bounds__(256, 4) void moe_gemm(const unsigned short* __restrict__ xbf,
                                                   const unsigned short* __restrict__ webf,
                                                   const float* __restrict__ be,
                                                   const int* __restrict__ counts,
                                                   const int* __restrict__ buckets,
                                                   float* __restrict__ out) {
  int lin = blockIdx.x;
  int swz = (lin & 7) * 512 + (lin >> 3);   // XCD-contiguous work id (bijective, 4096%8==0)
  int e = swz >> 8;                          // 256 work items per expert
  int rem = swz & 255;
  int o0 = (rem >> 6) * TN;                  // 4 n-tiles
  int m0 = (rem & 63) * TM;                  // 64 m-tiles

  int cnt = counts[e << 5];
  if (m0 >= cnt) return;

  __shared__ int toks[TM];

  int t = threadIdx.x;
  int lane = t & 63;
  int w = t >> 6;

  if (t < TM) {
    int r = m0 + t;
    toks[t] = (r < cnt) ? buckets[e * NTOK + r] : buckets[e * NTOK];
  }
  __syncthreads();   // the only block-wide sync

  int wm = (w & 1) * 32;        // 2 m-halves of 32
  int wn = (w >> 1) * 64;       // 2 n-halves of 64
  int fr = lane & 15;
  int quad = lane >> 4;

  // per-lane fragment base pointers (content == old LDS path, addressing unswizzled)
  const unsigned short* ap[2];
#pragma unroll
  for (int mt = 0; mt < 2; ++mt)
    ap[mt] = xbf + (size_t)toks[wm + mt * 16 + fr] * HDIM + quad * 8;
  const unsigned short* bp[4];
#pragma unroll
  for (int nt = 0; nt < 4; ++nt)
    bp[nt] = webf + ((size_t)e * ODIM + o0 + wn + nt * 16 + fr) * HDIM + quad * 8;

  // hoist bias loads
  float bias[4];
#pragma unroll
  for (int nt = 0; nt < 4; ++nt)
    bias[nt] = be[e * ODIM + o0 + wn + nt * 16 + fr];

  floatx4 acc[2][4] = {};

  // register double-buffer: frag[s&1]; unrolled loop -> static indexing (rule #20)
  bf16x8 af[2][2], bf[2][4];
#pragma unroll
  for (int mt = 0; mt < 2; ++mt) af[0][mt] = *(const bf16x8*)(ap[mt]);
#pragma unroll
  for (int nt = 0; nt < 4; ++nt) bf[0][nt] = *(const bf16x8*)(bp[nt]);

#pragma unroll
  for (int s = 0; s < HDIM / 32; ++s) {      // 16 k-steps of 32
    int cur = s & 1;
    int nxt = cur ^ 1;
    if (s < HDIM / 32 - 1) {
      int koff = (s + 1) * 32;
#pragma unroll
      for (int mt = 0; mt < 2; ++mt) af[nxt][mt] = *(const bf16x8*)(ap[mt] + koff);
#pragma unroll
      for (int nt = 0; nt < 4; ++nt) bf[nxt][nt] = *(const bf16x8*)(bp[nt] + koff);
    }
#pragma unroll
    for (int mt = 0; mt < 2; ++mt)
#pragma unroll
      for (int nt = 0; nt < 4; ++nt)
        acc[mt][nt] = __builtin_amdgcn_mfma_f32_16x16x32_bf16(af[cur][mt], bf[cur][nt],
                                                              acc[mt][nt], 0, 0, 0);
  }

  // epilogue: C/D layout col=lane&15, row=quad*4+i
  int rbase = wm + quad * 4;
#pragma unroll
  for (int nt = 0; nt < 4; ++nt) {
    int col = o0 + wn + nt * 16 + fr;
#pragma unroll
    for (int mt = 0; mt < 2; ++mt) {
#pragma unroll
      for (int i = 0; i < 4; ++i) {
        int rl = rbase + mt * 16 + i;
        if (m0 + rl < cnt) {
          out[(size_t)toks[rl] * ODIM + col] = acc[mt][nt][i] + bias[nt];
        }
      }
    }
  }
}

// ---------------- launch ----------------
// ws layout: [0, 2KB) strided counts | [4KB, +2MB) buckets | xbf 32MB | webf 8MB
#define WS_BUCKETS 4096
#define WS_XBF (WS_BUCKETS + NEXP * NTOK * 4)
#define WS_WEBF (WS_XBF + NTOK * HDIM * 2)

extern "C" void kernel_launch(void* const* d_in, const int* in_sizes, int n_in,
                              void* d_out, int out_size, void* d_ws, size_t ws_size,
                              hipStream_t stream) {
  const float* x  = (const float*)d_in[0];
  const float* Wg = (const float*)d_in[1];
  const float* bg = (const float*)d_in[2];
  const float* We = (const float*)d_in[3];
  const float* be = (const float*)d_in[4];
  float* out = (float*)d_out;
  char* ws = (char*)d_ws;

  int* counts = (int*)ws;
  int* buckets = (int*)(ws + WS_BUCKETS);
  unsigned short* xbf  = (unsigned short*)(ws + WS_XBF);
  unsigned short* webf = (unsigned short*)(ws + WS_WEBF);

  (void)hipMemsetAsync(counts, 0, NEXP * CSTRIDE * 4, stream);
  fused_prep<<<GATE_BLKS + CVT_BLKS, 256, 0, stream>>>(x, Wg, bg, We, counts, buckets, xbf, webf);
  moe_gemm<<<MTILES * (ODIM / TN) * NEXP, 256, 0, stream>>>(xbf, webf, be, counts, buckets, out);
}

// Round 10
// 186.868 us; speedup vs baseline: 1.3729x; 1.3729x over previous
//
#include <hip/hip_runtime.h>
#include <hip/hip_bf16.h>
#include <stdint.h>

// Problem constants (fixed by the reference)
#define NTOK 32768
#define HDIM 512
#define ODIM 512
#define NEXP 16

// GEMM tile config: TM=128 x TN=128, BK=32 (R1 body) + XCD swizzle (R8) + explicit vmcnt (R6).
// R9 (no-LDS direct fragments) failed 2.4x: scattered 16B/lane loads destroyed coalescing;
// LDS staging earns its barriers via coalescing + cross-wave sharing.
#define TM 128
#define TN 128
#define BK 32
#define MTILES 32   // 32 tiles x 128 rows = 4096 tokens/expert capacity (>40 sigma margin)

// counts[e] lives at counts[e*CSTRIDE]: one counter per 128B line -> 16-way parallel L2 atomics
#define CSTRIDE 32

#define GATE_BLKS (NTOK / 16)                      // 2048 gate blocks, 16 tokens each
#define CVT_BLKS (NEXP * ODIM * HDIM / 8 / 256)    // 2048 We-cvt blocks

typedef __bf16 bf16x8 __attribute__((ext_vector_type(8)));
typedef float  floatx4 __attribute__((ext_vector_type(4)));

__device__ __forceinline__ unsigned pk2(unsigned lo, unsigned hi) {
  return (lo >> 16) | (hi & 0xffff0000u);
}

__device__ __forceinline__ bf16x8 asbf8(uint4 u) { bf16x8 v; __builtin_memcpy(&v, &u, 16); return v; }

// exact 3-way bf16 truncation split of 8 floats: f = H + M + L exactly
__device__ __forceinline__ void split3(float4 a, float4 b, uint4* H, uint4* M, uint4* L) {
  float f[8] = {a.x, a.y, a.z, a.w, b.x, b.y, b.z, b.w};
  unsigned h[8], m[8], l[8];
#pragma unroll
  for (int j = 0; j < 8; ++j) {
    union { float F; unsigned U; } u; u.F = f[j];
    h[j] = u.U & 0xffff0000u;
    union { unsigned U; float F; } hv; hv.U = h[j];
    float r1 = f[j] - hv.F;                 // exact
    union { float F; unsigned U; } r1u; r1u.F = r1;
    m[j] = r1u.U & 0xffff0000u;
    union { unsigned U; float F; } mv; mv.U = m[j];
    float r2 = r1 - mv.F;                   // exact, fits bf16
    union { float F; unsigned U; } r2u; r2u.F = r2;
    l[j] = r2u.U;
  }
  H->x = pk2(h[0], h[1]); H->y = pk2(h[2], h[3]); H->z = pk2(h[4], h[5]); H->w = pk2(h[6], h[7]);
  M->x = pk2(m[0], m[1]); M->y = pk2(m[2], m[3]); M->z = pk2(m[4], m[5]); M->w = pk2(m[6], m[7]);
  L->x = pk2(l[0], l[1]); L->y = pk2(l[2], l[3]); L->z = pk2(l[4], l[5]); L->w = pk2(l[6], l[7]);
}

#define GLDS16(g, l) __builtin_amdgcn_global_load_lds( \
    (const __attribute__((address_space(1))) unsigned int*)(g), \
    (__attribute__((address_space(3))) unsigned int*)(l), 16, 0, 0)

// ---------------- fused prep: gate (16 tok/block) + We fp32->bf16 cvt (R8-exact) ------
__global__ __launch_bounds__(256, 4) void fused_prep(const float* __restrict__ x,
                                                     const float* __restrict__ Wg,
                                                     const float* __restrict__ bg,
                                                     const float* __restrict__ We,
                                                     int* __restrict__ counts,
                                                     int* __restrict__ buckets,
                                                     unsigned short* __restrict__ xbf,
                                                     unsigned short* __restrict__ webf) {
  __shared__ __align__(16) float red[4][16][20];   // [wave][token][expert], stride 20

  int bid = blockIdx.x;
  int t = threadIdx.x;

  if (bid >= GATE_BLKS) {
    // ---- We cvt block: 8 floats/thread, contiguous ----
    int i = (bid - GATE_BLKS) * 256 + t;
    const float4* src = (const float4*)We;
    float4 a = src[2 * i];
    float4 b = src[2 * i + 1];
    union { float F; unsigned U; } u[8] = {{a.x},{a.y},{a.z},{a.w},{b.x},{b.y},{b.z},{b.w}};
    uint4 o;
    o.x = pk2(u[0].U, u[1].U); o.y = pk2(u[2].U, u[3].U);
    o.z = pk2(u[4].U, u[5].U); o.w = pk2(u[6].U, u[7].U);
    ((uint4*)webf)[i] = o;
    return;
  }

  // ---- gate block: 16 tokens ----
  int lane = t & 63;
  int w = t >> 6;               // wave w covers k-range [w*128, w*128+128)
  int tok0 = bid * 16;
  int fr = lane & 15;           // A: token row; B: expert column
  int quad = lane >> 4;         // 8-float chunk within the 32-float k-step

  const float* xb0 = x + (size_t)(tok0 + fr) * HDIM + w * 128 + quad * 8;
  const float* wg0 = Wg + (size_t)fr * HDIM + w * 128 + quad * 8;

  floatx4 acc = {};

  // prefetch si=0 x
  float4 xa = *(const float4*)(xb0);
  float4 xv = *(const float4*)(xb0 + 4);

#pragma unroll
  for (int si = 0; si < 4; ++si) {
    int s = w * 4 + si;
    // B-frags from global (L2-hot 32KB), split in registers — bit-identical to staged path
    float4 wa = *(const float4*)(wg0 + si * 32);
    float4 wb = *(const float4*)(wg0 + si * 32 + 4);
    uint4 BH, BM, BL;
    split3(wa, wb, &BH, &BM, &BL);
    bf16x8 bh = asbf8(BH), bm = asbf8(BM), bl = asbf8(BL);

    float4 nxa, nxv;
    if (si < 3) {
      nxa = *(const float4*)(xb0 + (si + 1) * 32);
      nxv = *(const float4*)(xb0 + (si + 1) * 32 + 4);
    }

    uint4 H, M, L;
    split3(xa, xv, &H, &M, &L);
    *(uint4*)(xbf + (size_t)(tok0 + fr) * HDIM + s * 32 + quad * 8) = H;  // fused x->bf16
    bf16x8 ah = asbf8(H), am = asbf8(M), al = asbf8(L);
    acc = __builtin_amdgcn_mfma_f32_16x16x32_bf16(ah, bh, acc, 0, 0, 0);
    acc = __builtin_amdgcn_mfma_f32_16x16x32_bf16(ah, bm, acc, 0, 0, 0);
    acc = __builtin_amdgcn_mfma_f32_16x16x32_bf16(am, bh, acc, 0, 0, 0);
    acc = __builtin_amdgcn_mfma_f32_16x16x32_bf16(am, bm, acc, 0, 0, 0);
    acc = __builtin_amdgcn_mfma_f32_16x16x32_bf16(ah, bl, acc, 0, 0, 0);
    acc = __builtin_amdgcn_mfma_f32_16x16x32_bf16(al, bh, acc, 0, 0, 0);
    acc = __builtin_amdgcn_mfma_f32_16x16x32_bf16(am, bl, acc, 0, 0, 0);
    acc = __builtin_amdgcn_mfma_f32_16x16x32_bf16(al, bm, acc, 0, 0, 0);

    if (si < 3) { xa = nxa; xv = nxv; }
  }

  // cross-wave reduction: C/D layout col(lane&15)=expert, row=quad*4+i=token
#pragma unroll
  for (int i = 0; i < 4; ++i)
    red[w][quad * 4 + i][fr] = acc[i];
  __syncthreads();

  if (t < 16) {
    int r = t;    // token row
    float4 tot4[4];
#pragma unroll
    for (int eq = 0; eq < 4; ++eq) tot4[eq] = *(const float4*)&bg[eq * 4];
#pragma unroll
    for (int ww = 0; ww < 4; ++ww)
#pragma unroll
      for (int eq = 0; eq < 4; ++eq) {
        float4 v = *(const float4*)&red[ww][r][eq * 4];
        tot4[eq].x += v.x; tot4[eq].y += v.y; tot4[eq].z += v.z; tot4[eq].w += v.w;
      }
    float tot[16];
#pragma unroll
    for (int eq = 0; eq < 4; ++eq) {
      tot[eq * 4 + 0] = tot4[eq].x; tot[eq * 4 + 1] = tot4[eq].y;
      tot[eq * 4 + 2] = tot4[eq].z; tot[eq * 4 + 3] = tot4[eq].w;
    }
    float bv = tot[0]; int bi = 0;
#pragma unroll
    for (int e = 1; e < NEXP; ++e) if (tot[e] > bv) { bv = tot[e]; bi = e; }  // numpy first-index tie-break

    int token = tok0 + r;
    // staggered expert order: blocks hit different counters at any instant
    for (int ee = 0; ee < NEXP; ++ee) {
      int e = (ee + bid) & 15;
      unsigned long long mask = __ballot(bi == e);   // only lanes t<16 active
      if (mask) {
        int leader = __builtin_ctzll(mask);
        int base = 0;
        if (lane == leader) base = atomicAdd(&counts[e << 5], (int)__popcll(mask));
        base = __shfl(base, leader, 64);
        if (bi == e) {
          int rank = (int)__popcll(mask & ((1ull << lane) - 1ull));
          buckets[e * NTOK + base + rank] = token;
        }
      }
    }
  }
}

// ---------------- gathered-A GEMM: R1 128x128 body + XCD swizzle + explicit vmcnt -----
// 2048 blocks (32 m x 4 n x 16 e), bijective XCD swizzle (2048%8==0):
//   swz = (lin&7)*256 + (lin>>3)  -> each XCD gets 256 consecutive items = 2 full experts;
// expert working set (B 512KB + A ~2MB) fits the 4MB per-XCD L2 (R8: FETCH 53->29MB).
// TM=128 doubles MFMA-per-drain vs R8 (16 MFMA : 4 glds per wave-iter) and halves the
// B-panel L2 re-reads — the m93 "bigger tile amortizes staging" lever, now paired with
// the swizzle's shorter (L2) staging latency.
//
// LDS layout per 128x32 tile: cell(pair, slot), byte = pair*128 + slot*16, pair = row>>1,
// slot = (((row&1)<<2)|c) ^ (pair&7), c = 16B k-chunk. glds dest linear; inverse swizzle
// on the per-lane GLOBAL source (rule #21). Fragment ds_read_b128 = 2 lanes/bank (free).
__global__ __launch_bounds__(256, 2) void moe_gemm(const unsigned short* __restrict__ xbf,
                                                   const unsigned short* __restrict__ webf,
                                                   const float* __restrict__ be,
                                                   const int* __restrict__ counts,
                                                   const int* __restrict__ buckets,
                                                   float* __restrict__ out) {
  int lin = blockIdx.x;
  int swz = (lin & 7) * 256 + (lin >> 3);   // XCD-contiguous work id (bijective)
  int e = swz >> 7;                          // 128 work items per expert
  int rem = swz & 127;
  int o0 = (rem >> 5) * TN;                  // 4 n-tiles
  int m0 = (rem & 31) * TM;                  // 32 m-tiles

  int cnt = counts[e << 5];
  if (m0 >= cnt) return;

  __shared__ __align__(16) unsigned short As[2][TM * BK];   // 2 x 8 KB
  __shared__ __align__(16) unsigned short Bs[2][TN * BK];   // 2 x 8 KB
  __shared__ int toks[TM];

  int t = threadIdx.x;
  int lane = t & 63;
  int w = t >> 6;

  if (t < TM) {
    int r = m0 + t;
    toks[t] = (r < cnt) ? buckets[e * NTOK + r] : buckets[e * NTOK];
  }
  __syncthreads();

  // staging decode: one glds covers 16 rows x 4 chunks = 64 lanes.
  // lane -> (pl = lane>>3, sl = lane&7); slog = sl ^ pl (pair&7 == pl since row-block
  // bases are multiples of 16); rsub = 2*pl + (slog>>2); chunk = slog&3.
  int pl = lane >> 3;
  int sl = lane & 7;
  int slog = sl ^ pl;
  int rsub = 2 * pl + (slog >> 2);
  int cch = slog & 3;
  const unsigned short* agp[2];
  const unsigned short* bgp[2];
#pragma unroll
  for (int j = 0; j < 2; ++j) {
    int row = w * 32 + j * 16 + rsub;
    agp[j] = xbf + (size_t)toks[row] * HDIM + cch * 8;
    bgp[j] = webf + ((size_t)e * ODIM + o0 + row) * HDIM + cch * 8;
  }

  int wm = (w & 1) * 64;
  int wn = (w >> 1) * 64;
  int fr = lane & 15;
  int quad = lane >> 4;

  // fragment read offsets (ushort units): row m, chunk quad ->
  //   pair*64 + ((((m&1)<<2)|quad) ^ (pair&7))*8
  int aoff[4], boff[4];
#pragma unroll
  for (int mt = 0; mt < 4; ++mt) {
    int m = wm + mt * 16 + fr;
    int pr = m >> 1;
    aoff[mt] = pr * 64 + (((((m & 1) << 2) | quad) ^ (pr & 7)) << 3);
    int n = wn + mt * 16 + fr;
    int pn = n >> 1;
    boff[mt] = pn * 64 + (((((n & 1) << 2) | quad) ^ (pn & 7)) << 3);
  }

  // hoist bias loads: complete long before the epilogue needs them
  float bias[4];
#pragma unroll
  for (int nt = 0; nt < 4; ++nt)
    bias[nt] = be[e * ODIM + o0 + wn + nt * 16 + fr];

  floatx4 acc[4][4] = {};

  int dst = w * 1024;   // ushort units; +j*512 per instr (each glds writes 1 KB)

  // prologue: fill buffer 0 (k=0)
#pragma unroll
  for (int j = 0; j < 2; ++j) {
    GLDS16(agp[j], As[0] + dst + j * 512);
    GLDS16(bgp[j], Bs[0] + dst + j * 512);
  }

  for (int k = 0; k < HDIM / BK; ++k) {
    int p = k & 1;
    // explicit drain: all of this wave's outstanding glds writes landed in LDS
    asm volatile("s_waitcnt vmcnt(0)" ::: "memory");
    __syncthreads();   // buf p ready everywhere; buf 1-p reads (iter k-1) done
    if (k < HDIM / BK - 1) {
      int koff = (k + 1) * BK;
#pragma unroll
      for (int j = 0; j < 2; ++j) {
        GLDS16(agp[j] + koff, As[1 - p] + dst + j * 512);
        GLDS16(bgp[j] + koff, Bs[1 - p] + dst + j * 512);
      }
    }

    bf16x8 af[4], bfr[4];
#pragma unroll
    for (int mt = 0; mt < 4; ++mt)
      af[mt] = *(const bf16x8*)(As[p] + aoff[mt]);
#pragma unroll
    for (int nt = 0; nt < 4; ++nt)
      bfr[nt] = *(const bf16x8*)(Bs[p] + boff[nt]);
#pragma unroll
    for (int mt = 0; mt < 4; ++mt)
#pragma unroll
      for (int nt = 0; nt < 4; ++nt)
        acc[mt][nt] = __builtin_amdgcn_mfma_f32_16x16x32_bf16(af[mt], bfr[nt], acc[mt][nt], 0, 0, 0);
  }

  // epilogue: C/D layout col=lane&15, row=quad*4+i
  int rbase = wm + quad * 4;
#pragma unroll
  for (int nt = 0; nt < 4; ++nt) {
    int col = o0 + wn + nt * 16 + fr;
#pragma unroll
    for (int mt = 0; mt < 4; ++mt) {
#pragma unroll
      for (int i = 0; i < 4; ++i) {
        int rl = rbase + mt * 16 + i;
        if (m0 + rl < cnt) {
          out[(size_t)toks[rl] * ODIM + col] = acc[mt][nt][i] + bias[nt];
        }
      }
    }
  }
}

// ---------------- launch ----------------
// ws layout: [0, 2KB) strided counts | [4KB, +2MB) buckets | xbf 32MB | webf 8MB
#define WS_BUCKETS 4096
#define WS_XBF (WS_BUCKETS + NEXP * NTOK * 4)
#define WS_WEBF (WS_XBF + NTOK * HDIM * 2)

extern "C" void kernel_launch(void* const* d_in, const int* in_sizes, int n_in,
                              void* d_out, int out_size, void* d_ws, size_t ws_size,
                              hipStream_t stream) {
  const float* x  = (const float*)d_in[0];
  const float* Wg = (const float*)d_in[1];
  const float* bg = (const float*)d_in[2];
  const float* We = (const float*)d_in[3];
  const float* be = (const float*)d_in[4];
  float* out = (float*)d_out;
  char* ws = (char*)d_ws;

  int* counts = (int*)ws;
  int* buckets = (int*)(ws + WS_BUCKETS);
  unsigned short* xbf  = (unsigned short*)(ws + WS_XBF);
  unsigned short* webf = (unsigned short*)(ws + WS_WEBF);

  (void)hipMemsetAsync(counts, 0, NEXP * CSTRIDE * 4, stream);
  fused_prep<<<GATE_BLKS + CVT_BLKS, 256, 0, stream>>>(x, Wg, bg, We, counts, buckets, xbf, webf);
  moe_gemm<<<MTILES * (ODIM / TN) * NEXP, 256, 0, stream>>>(xbf, webf, be, counts, buckets, out);
}